// Round 1
// baseline (409.634 us; speedup 1.0000x reference)
//
#include <hip/hip_runtime.h>

// CTC batch cost (forward algorithm), faithful to K.ctc_batch_cost with full lengths.
// Shapes fixed by the problem: B=512, T=512, C=128 (blank=C-1), L=64, S=2L+1=129.
//
// Mapping: one block per batch sample b. 128 threads (2 waves).
//  - ext/skip tables for the blank-interleaved label sequence in LDS (built once).
//  - per timestep t: threads coalesced-load y_pred[b,t,:] (128 floats, 1/lane),
//    write log(p+eps) to LDS, then each state s does the 3-term logsumexp
//    recurrence reading the double-buffered alpha in LDS.
//  - t+1 row load is issued right after consuming row t (software pipeline:
//    latency covered by barrier + compute phase).
// alpha buffers have 2 leading NEG pad slots so s-1 / s-2 need no branches.

constexpr int Tn = 512;
constexpr int Cn = 128;
constexpr int Ln = 64;
constexpr int Sn = 2 * Ln + 1;   // 129
constexpr float NEGF = -1e9f;
constexpr float EPSF = 1e-7f;

__global__ __launch_bounds__(128)
void ctc_fwd(const int* __restrict__ y_true,
             const float* __restrict__ y_pred,
             float* __restrict__ out)
{
    const int b = blockIdx.x;
    const int tid = threadIdx.x;

    __shared__ float lp_row[Cn];
    __shared__ float alpha[2][Sn + 2];   // states stored at [s+2]; [0],[1] = NEG pad
    __shared__ int   ext_s[Sn];
    __shared__ int   skip_s[Sn];

    const float* base = y_pred + (size_t)b * Tn * Cn;
    const int*   lab  = y_true + b * Ln;

    // Extended label sequence: even s -> blank (C-1), odd s -> label[s/2]
    for (int s = tid; s < Sn; s += 128)
        ext_s[s] = (s & 1) ? lab[s >> 1] : (Cn - 1);

    if (tid < 2) { alpha[0][tid] = NEGF; alpha[1][tid] = NEGF; }

    // row t=0 (issued early; consumed after barrier)
    float p0 = base[tid];
    __syncthreads();   // ext_s ready

    // skip[s]: s>=2 && ext[s]!=blank && ext[s]!=ext[s-2]
    for (int s = tid; s < Sn; s += 128) {
        int sk = 0;
        if (s >= 2) {
            int e = ext_s[s];
            sk = (e != Cn - 1) && (e != ext_s[s - 2]);
        }
        skip_s[s] = sk;
    }

    lp_row[tid] = __logf(p0 + EPSF);
    __syncthreads();   // lp_row + skip_s ready

    // alpha at t=0: only states 0 and 1 reachable
    for (int s = tid; s < Sn; s += 128) {
        float a = NEGF;
        if (s < 2) a = lp_row[ext_s[s]];
        alpha[0][s + 2] = a;
    }

    int cur = 0;
    float pv = base[Cn + tid];   // prefetch row t=1
    for (int t = 1; t < Tn; ++t) {
        __syncthreads();   // B1: all reads of lp_row / alpha from prev step done
        lp_row[tid] = __logf(pv + EPSF);
        if (t + 1 < Tn)
            pv = base[(size_t)(t + 1) * Cn + tid];   // prefetch next row
        __syncthreads();   // B2: lp_row ready

        const int nxt = cur ^ 1;
        for (int s = tid; s < Sn; s += 128) {
            float a1 = alpha[cur][s + 2];                     // stay
            float a2 = alpha[cur][s + 1];                     // advance 1
            float a3 = skip_s[s] ? alpha[cur][s] : NEGF;      // advance 2
            float m  = fmaxf(a1, fmaxf(a2, a3));
            float sum = __expf(a1 - m) + __expf(a2 - m) + __expf(a3 - m);
            alpha[nxt][s + 2] = lp_row[ext_s[s]] + m + __logf(sum);
        }
        cur = nxt;
    }

    __syncthreads();
    if (tid == 0) {
        float a1 = alpha[cur][Sn];       // state S-2 (last label)
        float a2 = alpha[cur][Sn + 1];   // state S-1 (last blank)
        float m  = fmaxf(a1, a2);
        float ll = m + __logf(__expf(a1 - m) + __expf(a2 - m));
        out[b] = -ll;
    }
}

extern "C" void kernel_launch(void* const* d_in, const int* in_sizes, int n_in,
                              void* d_out, int out_size, void* d_ws, size_t ws_size,
                              hipStream_t stream)
{
    const int*   y_true = (const int*)d_in[0];    // [B, L] int32
    const float* y_pred = (const float*)d_in[1];  // [B, T, C] float32
    float*       out    = (float*)d_out;          // [B, 1] float32

    const int B = out_size;   // 512
    ctc_fwd<<<dim3(B), dim3(128), 0, stream>>>(y_true, y_pred, out);
}

// Round 2
// 235.047 us; speedup vs baseline: 1.7428x; 1.7428x over previous
//
#include <hip/hip_runtime.h>

// CTC batch cost, forward algorithm. B=512, T=512, C=128 (blank=127), L=64, S=129.
//
// R2 design: ONE WAVE PER SAMPLE, no LDS, no barriers.
//  - lane i owns states 2i, 2i+1; lane 63 additionally owns state 128.
//    s-1 of odd state = own a0; s-1/s-2 across lanes = one __shfl_up(a1,1)/step.
//  - gather indices are time-invariant: even states read the blank channel
//    (broadcast via __shfl(row.y, 63)); odd states read lab[i] via two
//    ds_bpermute on the register-held row (addr precomputed).
//  - rows loaded as float2 (lane -> channels 2*lane, 2*lane+1), 8-deep
//    register prefetch ring to cover ~900-cycle HBM latency.
//  - alpha kept in log2 domain (v_exp_f32/v_log_f32 are 2^x / log2 natively);
//    one *ln2 at the very end.

constexpr int Tn = 512;
constexpr int Cn = 128;
constexpr int Ln = 64;
constexpr float NEGF = -1e9f;
constexpr float EPSF = 1e-7f;
constexpr float LN2F = 0.6931471805599453f;

#if __has_builtin(__builtin_amdgcn_exp2f)
#define EXP2F(x) __builtin_amdgcn_exp2f(x)
#else
#define EXP2F(x) __expf((x) * 0.6931471805599453f)
#endif
#if __has_builtin(__builtin_amdgcn_logf)
#define LOG2F(x) __builtin_amdgcn_logf(x)
#else
#define LOG2F(x) (__logf(x) * 1.4426950408889634f)
#endif

__global__ __launch_bounds__(64)
void ctc_fwd(const int* __restrict__ y_true,
             const float* __restrict__ y_pred,
             float* __restrict__ out)
{
    const int b    = blockIdx.x;
    const int lane = threadIdx.x;   // 0..63

    // row t as float2: lane holds channels 2*lane, 2*lane+1
    const float2* row = (const float2*)(y_pred + (size_t)b * Tn * Cn);

    // Per-lane label (L=64: one per lane) and time-invariant gather setup
    const int  lab   = y_true[b * Ln + lane];          // ext[2*lane+1]
    const int  labp  = __shfl_up(lab, 1, 64);
    const bool skip  = (lane > 0) && (lab != labp);    // skip for odd state
    const int  baddr = (lab >> 1) << 2;                // bpermute source-lane*4
    const bool bhi   = (lab & 1) != 0;                 // which half of float2

    // log2(p+eps) for the two channels this step needs: blank (127) + lab
    auto lp_pair = [&](float2 p, float& lpb, float& lpl) {
        float pb = __shfl(p.y, 63, 64);                // channel 127 = blank
        lpb = LOG2F(pb + EPSF);
        int lo = __builtin_amdgcn_ds_bpermute(baddr, __float_as_int(p.x));
        int hi = __builtin_amdgcn_ds_bpermute(baddr, __float_as_int(p.y));
        float pl = bhi ? __int_as_float(hi) : __int_as_float(lo);
        lpl = LOG2F(pl + EPSF);
    };

    // Prefetch: row 0 + ring of rows 1..8
    float2 p0 = row[lane];
    float2 pv[8];
    #pragma unroll
    for (int k = 0; k < 8; ++k) pv[k] = row[(k + 1) * 64 + lane];

    // t = 0 init: only states 0 and 1 reachable (both on lane 0)
    float a0, a1, aX;   // states 2i, 2i+1, 128(lane63) — log2 domain
    {
        float lpb, lpl;
        lp_pair(p0, lpb, lpl);
        a0 = (lane == 0) ? lpb : NEGF;
        a1 = (lane == 0) ? lpl : NEGF;
        aX = NEGF;
    }

    auto step = [&](float2 p) {
        float lpb, lpl;
        lp_pair(p, lpb, lpl);
        float up1 = __shfl_up(a1, 1, 64);              // alpha[2i-1]
        if (lane == 0) up1 = NEGF;
        // even state 2i (blank): stay + advance-1, never skip
        float m0 = fmaxf(a0, up1);
        float n0 = lpb + m0 + LOG2F(EXP2F(a0 - m0) + EXP2F(up1 - m0));
        // odd state 2i+1 (label): stay + advance-1(own a0) + skip(up1)
        float a3 = skip ? up1 : NEGF;
        float m1 = fmaxf(fmaxf(a1, a0), a3);
        float n1 = lpl + m1 +
                   LOG2F(EXP2F(a1 - m1) + EXP2F(a0 - m1) + EXP2F(a3 - m1));
        // state 128 (blank; meaningful on lane 63 only — junk elsewhere)
        float mX = fmaxf(aX, a1);
        float nX = lpb + mX + LOG2F(EXP2F(aX - mX) + EXP2F(a1 - mX));
        a0 = n0; a1 = n1; aX = nX;
    };

    // Main loop: t = 1..504 (63 blocks of 8, ring indices compile-time const)
    for (int tb = 1; tb <= 497; tb += 8) {
        #pragma unroll
        for (int u = 0; u < 8; ++u) {
            step(pv[u]);
            int tn = tb + u + 8;                       // refill with row t+8
            tn = tn > 511 ? 511 : tn;                  // clamped (redundant ok)
            pv[u] = row[tn * 64 + lane];
        }
    }
    // Epilogue: t = 505..511 in pv[0..6]
    #pragma unroll
    for (int u = 0; u < 7; ++u) step(pv[u]);

    // -log P = -(lsexp2(alpha[127], alpha[128])) * ln2 ; both live on lane 63
    if (lane == 63) {
        float m  = fmaxf(a1, aX);
        float ll = m + LOG2F(EXP2F(a1 - m) + EXP2F(aX - m));
        out[b] = -ll * LN2F;
    }
}

extern "C" void kernel_launch(void* const* d_in, const int* in_sizes, int n_in,
                              void* d_out, int out_size, void* d_ws, size_t ws_size,
                              hipStream_t stream)
{
    const int*   y_true = (const int*)d_in[0];    // [B, L] int32
    const float* y_pred = (const float*)d_in[1];  // [B, T, C] float32
    float*       out    = (float*)d_out;          // [B, 1] float32

    const int B = out_size;   // 512
    ctc_fwd<<<dim3(B), dim3(64), 0, stream>>>(y_true, y_pred, out);
}

// Round 3
// 210.862 us; speedup vs baseline: 1.9427x; 1.1147x over previous
//
#include <hip/hip_runtime.h>

// CTC batch cost, forward algorithm. B=512, T=512, C=128 (blank=127), L=64, S=129.
//
// R3: one wave per sample; ZERO DS ops in the serial alpha chain.
//  - lane i owns states 2i+1 (label, aA) and 2i+2 (blank, aB); state 0 is a
//    uniform scalar accumulator aZ (alpha[0] += lp_blank each step, no lse).
//    Both cross-lane neighbors come from lane i-1 -> one DPP wave_shr:1 each
//    (VALU pipe, ~4 cyc) instead of LDS shuffles (~100 cyc).
//  - 3-stage software pipeline, all ring indices compile-time after unroll:
//      slot t: consume lp(row t) | finalize lpl(row t+4) from bpermute ring |
//              logs + readlane + issue bpermutes for row t+8 | load row t+16.
//    DS (bpermute) latency gets 4 slots to complete, off the alpha chain;
//    HBM latency gets 16 slots.
//  - log2 domain throughout (v_exp_f32 / v_log_f32 are natively 2^x / log2x);
//    single *ln2 at the end. 2-term lse via 1+exp2(min-max).

constexpr int Tn = 512;
constexpr int Cn = 128;
constexpr int Ln = 64;
constexpr float NEGF = -1e9f;
constexpr float EPSF = 1e-7f;
constexpr float LN2F = 0.6931471805599453f;

#define EXP2F(x) __builtin_amdgcn_exp2f(x)
#define LOG2F(x) __builtin_amdgcn_logf(x)

// whole-wave shift right by 1: lane i <- lane i-1 (lane 0 gets 0; fixed up after)
__device__ __forceinline__ float dpp_shr1(float x) {
    return __int_as_float(__builtin_amdgcn_update_dpp(
        0, __float_as_int(x), 0x138 /*wave_shr:1*/, 0xF, 0xF, true));
}

__global__ __launch_bounds__(64)
void ctc_fwd(const int* __restrict__ y_true,
             const float* __restrict__ y_pred,
             float* __restrict__ out)
{
    const int b    = blockIdx.x;
    const int lane = threadIdx.x;   // 0..63

    // row t as float2: lane holds channels 2*lane, 2*lane+1
    const float2* __restrict__ row = (const float2*)(y_pred + (size_t)b * Tn * Cn);

    const int  lab   = y_true[b * Ln + lane];        // label of state 2*lane+1
    const int  labp  = __shfl_up(lab, 1, 64);        // prologue-only DS, fine
    const bool skip  = (lane > 0) && (lab != labp);
    const int  baddr = (lab >> 1) << 2;              // bpermute byte addr (src lane)
    const bool bhi   = (lab & 1) != 0;               // which float2 component
    const bool l0    = (lane == 0);

    float2 pv[16];                  // row ring: entry (r-1)&15 holds row r
    float  bpLo[4], bpHi[4];        // bpermuted logs in flight (rows +4..+8)
    float  lpLv[4];                 // finalized log2 p[lab]  (rows +1..+4)
    float  lpbv[8];                 // log2 p[blank] (uniform) (rows +1..+8)

    float aA, aB, aZ;               // alpha[2i+1], alpha[2i+2], alpha[0] (log2)

    // ---- prologue: row 0 init + prime rings with rows 1..16 ----
    float2 p0 = row[lane];
    #pragma unroll
    for (int k = 0; k < 16; ++k) pv[k] = row[(1 + k) * 64 + lane];

    {
        float g0 = LOG2F(p0.x + EPSF);
        float g1 = LOG2F(p0.y + EPSF);
        aZ = __int_as_float(__builtin_amdgcn_readlane(__float_as_int(g1), 63));
        float bl = __int_as_float(__builtin_amdgcn_ds_bpermute(baddr, __float_as_int(g0)));
        float bh = __int_as_float(__builtin_amdgcn_ds_bpermute(baddr, __float_as_int(g1)));
        float lpl0 = bhi ? bh : bl;
        aA = l0 ? lpl0 : NEGF;      // alpha[1] = lp[lab0] on lane 0
        aB = NEGF;                  // states >= 2 unreachable at t=0
    }

    #pragma unroll
    for (int j = 0; j < 8; ++j) {   // rows 1..8
        float g0 = LOG2F(pv[j].x + EPSF);
        float g1 = LOG2F(pv[j].y + EPSF);
        lpbv[j] = __int_as_float(__builtin_amdgcn_readlane(__float_as_int(g1), 63));
        float bl = __int_as_float(__builtin_amdgcn_ds_bpermute(baddr, __float_as_int(g0)));
        float bh = __int_as_float(__builtin_amdgcn_ds_bpermute(baddr, __float_as_int(g1)));
        if (j < 4) lpLv[j] = bhi ? bh : bl;          // rows 1..4 finalized
        else { bpLo[j - 4] = bl; bpHi[j - 4] = bh; } // rows 5..8 in flight
    }

    // ---- per-slot body pieces (u = (t-1)&15, compile-time after unroll) ----
    auto consume = [&](int u) {
        float lpb = lpbv[u & 7];
        float lpl = lpLv[u & 3];
        float upA = dpp_shr1(aA);   // alpha[2i-1]
        float upB = dpp_shr1(aB);   // alpha[2i]
        upA = l0 ? NEGF : upA;
        upB = l0 ? aZ   : upB;
        // label state 2i+1: stay aA, advance upB, skip? upA
        float a3 = skip ? upA : NEGF;
        float m1 = fmaxf(fmaxf(aA, upB), a3);
        float s1 = EXP2F(aA - m1) + EXP2F(upB - m1) + EXP2F(a3 - m1);
        float nA = lpl + m1 + LOG2F(s1);
        // blank state 2i+2: stay aB, advance aA (own) — 2-term lse
        float m2 = fmaxf(aB, aA);
        float n2 = fminf(aB, aA);
        float nB = lpb + m2 + LOG2F(1.0f + EXP2F(n2 - m2));
        aZ += lpb;                  // state 0: only self-loop
        aA = nA; aB = nB;
    };
    auto stageB = [&](int u) {      // finalize lpl for row t+4
        lpLv[u & 3] = bhi ? bpHi[u & 3] : bpLo[u & 3];
    };
    auto stageA = [&](int u) {      // logs + issue bpermutes for row t+8
        float2 p = pv[(u + 8) & 15];
        float g0 = LOG2F(p.x + EPSF);
        float g1 = LOG2F(p.y + EPSF);
        lpbv[u & 7] = __int_as_float(__builtin_amdgcn_readlane(__float_as_int(g1), 63));
        bpLo[u & 3] = __int_as_float(__builtin_amdgcn_ds_bpermute(baddr, __float_as_int(g0)));
        bpHi[u & 3] = __int_as_float(__builtin_amdgcn_ds_bpermute(baddr, __float_as_int(g1)));
    };

    // ---- main: t = 1..496 (31 x 16 slots) ----
    int t = 1;
    for (int blk = 0; blk < 31; ++blk) {
        #pragma unroll
        for (int u = 0; u < 16; ++u, ++t) {
            consume(u);
            stageB(u);
            stageA(u);
            int rn = t + 16; rn = rn > 511 ? 511 : rn;   // clamped dup, harmless
            pv[u] = row[rn * 64 + lane];
        }
    }
    // ---- epilogue: t = 497..511 (no more loads) ----
    #pragma unroll
    for (int u = 0; u < 15; ++u, ++t) {
        consume(u);
        stageB(u);
        stageA(u);   // late outputs never consumed; reads are valid/harmless
    }

    // ll = lse2(alpha[127], alpha[128]); both live on lane 63
    float m  = fmaxf(aA, aB);
    float n  = fminf(aA, aB);
    float ll = m + LOG2F(1.0f + EXP2F(n - m));
    if (lane == 63) out[b] = -ll * LN2F;
}

extern "C" void kernel_launch(void* const* d_in, const int* in_sizes, int n_in,
                              void* d_out, int out_size, void* d_ws, size_t ws_size,
                              hipStream_t stream)
{
    const int*   y_true = (const int*)d_in[0];    // [B, L] int32
    const float* y_pred = (const float*)d_in[1];  // [B, T, C] float32
    float*       out    = (float*)d_out;          // [B, 1] float32

    const int B = out_size;   // 512
    ctc_fwd<<<dim3(B), dim3(64), 0, stream>>>(y_true, y_pred, out);
}

// Round 4
// 200.105 us; speedup vs baseline: 2.0471x; 1.0538x over previous
//
#include <hip/hip_runtime.h>

// CTC batch cost, forward algorithm. B=512, T=512, C=128 (blank=127), L=64, S=129.
//
// R4: one wave per sample; zero DS in the alpha chain (DPP neighbors); and a
// DEEP software pipeline so no stage ever waits:
//   slot t:  consume row t            (alpha update, VALU/trans only)
//          | stageB: finalize row t+4 (select bpermuted raw prob -> log2)
//          | stageA: issue bpermutes for row t+8 (raw probs, pure DS issue)
//          | load row t+32 into the 32-row register ring (global, 24-slot
//            distance to first use ~= 1800+ cyc >> 900-cyc HBM latency)
// R3's 8-slot load->use distance stalled on vmcnt every step; this fixes it.
// All ring indices are compile-time after unroll. log2 domain throughout
// (v_exp_f32/v_log_f32 are natively 2^x/log2x); one *ln2 at the end.
// lane i owns states 2i+1 (label, aA) and 2i+2 (blank, aB); state 0 is the
// uniform scalar accumulator aZ (self-loop only: aZ += lp_blank).

constexpr float NEGF = -1e9f;
constexpr float EPSF = 1e-7f;
constexpr float LN2F = 0.6931471805599453f;

#define EXP2F(x) __builtin_amdgcn_exp2f(x)
#define LOG2F(x) __builtin_amdgcn_logf(x)

// whole-wave shift right by 1: lane i <- lane i-1 (lane 0 gets 0; fixed up after)
__device__ __forceinline__ float dpp_shr1(float x) {
    return __int_as_float(__builtin_amdgcn_update_dpp(
        0, __float_as_int(x), 0x138 /*wave_shr:1*/, 0xF, 0xF, true));
}
__device__ __forceinline__ float bperm(int addr, float x) {
    return __int_as_float(__builtin_amdgcn_ds_bpermute(addr, __float_as_int(x)));
}
__device__ __forceinline__ float rdl63(float x) {
    return __int_as_float(__builtin_amdgcn_readlane(__float_as_int(x), 63));
}

__global__ __launch_bounds__(64)
void ctc_fwd(const int* __restrict__ y_true,
             const float* __restrict__ y_pred,
             float* __restrict__ out)
{
    const int b    = blockIdx.x;
    const int lane = threadIdx.x;   // 0..63

    // row t as float2: lane holds channels 2*lane, 2*lane+1
    const float2* __restrict__ rowp =
        (const float2*)(y_pred + (size_t)b * 512 * 128) + lane;

    const int  lab   = y_true[b * 64 + lane];   // label of state 2*lane+1
    const int  labp  = __shfl_up(lab, 1, 64);   // prologue-only DS
    const bool skip  = (lane > 0) && (lab != labp);
    const int  baddr = (lab >> 1) << 2;         // bpermute byte addr
    const bool bhi   = (lab & 1) != 0;          // which float2 component
    const bool l0    = (lane == 0);

    float2 pv[32];                  // raw-prob row ring: pv[r & 31] = row r
    float  bpLo[4], bpHi[4];        // bpermuted RAW probs in flight (+4..+8)
    float  lpLv[4], lpbv[4];        // finalized log2 p[lab] / p[blank] (+1..+4)
    float  aA, aB, aZ;              // alpha[2i+1], alpha[2i+2], alpha[0] (log2)

    // ---- prologue ----
    float2 p0 = rowp[0];
    #pragma unroll
    for (int r = 1; r <= 32; ++r) pv[r & 31] = rowp[r * 64];

    {   // t = 0 init: only states 0 and 1 reachable
        float blo = bperm(baddr, p0.x);
        float bh  = bperm(baddr, p0.y);
        float pl  = bhi ? bh : blo;
        aZ = LOG2F(rdl63(p0.y) + EPSF);
        aA = l0 ? LOG2F(pl + EPSF) : NEGF;
        aB = NEGF;
    }
    #pragma unroll
    for (int r = 1; r <= 4; ++r) {  // rows 1..4 fully finalized
        float2 p  = pv[r & 31];
        float blo = bperm(baddr, p.x);
        float bh  = bperm(baddr, p.y);
        float pl  = bhi ? bh : blo;
        lpLv[r & 3] = LOG2F(pl + EPSF);
        lpbv[r & 3] = LOG2F(rdl63(p.y) + EPSF);
    }
    #pragma unroll
    for (int r = 5; r <= 8; ++r) {  // rows 5..8: bpermutes in flight
        float2 p = pv[r & 31];
        bpLo[r & 3] = bperm(baddr, p.x);
        bpHi[r & 3] = bperm(baddr, p.y);
    }

    // ---- per-slot body; u = t & 31 is compile-time after unroll ----
    auto slot = [&](int t, int u, bool doLoad) {
        // consume row t
        float lpb = lpbv[u & 3];
        float lpl = lpLv[u & 3];
        float upA = dpp_shr1(aA);               // alpha[2i-1]
        float upB = dpp_shr1(aB);               // alpha[2i]
        upA = l0 ? NEGF : upA;
        upB = l0 ? aZ   : upB;
        // label state 2i+1: stay aA, advance upB, skip? upA
        float a3 = skip ? upA : NEGF;
        float m1 = fmaxf(fmaxf(aA, upB), a3);
        float s1 = EXP2F(aA - m1) + EXP2F(upB - m1) + EXP2F(a3 - m1);
        float nA = lpl + m1 + LOG2F(s1);
        // blank state 2i+2: stay aB, advance aA (own) — 2-term lse
        float m2 = fmaxf(aB, aA);
        float n2 = fminf(aB, aA);
        float nB = lpb + m2 + LOG2F(1.0f + EXP2F(n2 - m2));
        aZ += lpb;
        aA = nA; aB = nB;
        // stageB: finalize row t+4 (bpermute results had 4 slots to land)
        {
            int q = (u + 4) & 3;
            float pl = bhi ? bpHi[q] : bpLo[q];
            lpLv[q] = LOG2F(pl + EPSF);
            lpbv[q] = LOG2F(rdl63(pv[(u + 4) & 31].y) + EPSF);
        }
        // stageA: issue bpermutes for row t+8 (raw; load had 24 slots to land)
        {
            int q = (u + 8) & 3;
            float2 p = pv[(u + 8) & 31];
            bpLo[q] = bperm(baddr, p.x);
            bpHi[q] = bperm(baddr, p.y);
        }
        // load row t+32 (wrap &511 keeps it in-bounds; wrapped rows never consumed)
        if (doLoad) pv[u] = rowp[((t + 32) & 511) * 64];
    };

    // ---- main: t = 1..480 (15 x 32 slots, with loads) ----
    for (int blk = 0; blk < 15; ++blk) {
        int t0 = 1 + blk * 32;
        #pragma unroll
        for (int i = 0; i < 32; ++i)
            slot(t0 + i, (1 + i) & 31, true);
    }
    // ---- epilogue: t = 481..511 (31 slots, no loads) ----
    {
        int t0 = 481;
        #pragma unroll
        for (int i = 0; i < 31; ++i)
            slot(t0 + i, (1 + i) & 31, false);
    }

    // ll = lse2(alpha[127], alpha[128]); both live on lane 63
    float m  = fmaxf(aA, aB);
    float n  = fminf(aA, aB);
    float ll = m + LOG2F(1.0f + EXP2F(n - m));
    if (lane == 63) out[b] = -ll * LN2F;
}

extern "C" void kernel_launch(void* const* d_in, const int* in_sizes, int n_in,
                              void* d_out, int out_size, void* d_ws, size_t ws_size,
                              hipStream_t stream)
{
    const int*   y_true = (const int*)d_in[0];    // [B, L] int32
    const float* y_pred = (const float*)d_in[1];  // [B, T, C] float32
    float*       out    = (float*)d_out;          // [B, 1] float32

    const int B = out_size;   // 512
    ctc_fwd<<<dim3(B), dim3(64), 0, stream>>>(y_true, y_pred, out);
}

// Round 6
// 191.709 us; speedup vs baseline: 2.1367x; 1.0438x over previous
//
#include <hip/hip_runtime.h>

// CTC batch cost, forward algorithm. B=512, T=512, C=128 (blank=127), L=64, S=129.
//
// R6 = R5 with the DPP helper templated (dpp_ctrl must be a compile-time
// constant — R5's runtime arg failed to build).
//
// LINEAR (probability) domain — zero transcendentals, zero DS ops in the
// 512-step serial loop:
//     nA = pl * (aA + upB + skipf*upA)      (label state 2i+1)
//     nB = pb * (aB + aA)                   (blank state 2i+2)
//     aZ *= pb                              (state 0, uniform)
// Cross-lane neighbors via DPP wave_shr:1 (VALU). Underflow handled by a
// uniform power-of-2 rescale every 8 steps: DPP wave-max measured at phase 3,
// applied (stale, off-chain) at phase 7; scale built from the max's exponent
// field with integer ops targeting max ~= 2^60; shift count accumulated and
// folded in with one log2 at the end.
// Probabilities via per-lane GLOBAL gathers (p[lab_i]) + broadcast load
// (p[blank]); 32-row register rings cover HBM latency.
// lane i owns states 2i+1 (aA) and 2i+2 (aB).

constexpr float EPSF = 1e-7f;
constexpr float LN2F = 0.6931471805599453f;

template<int CTRL>
__device__ __forceinline__ float dpp_mov(float x) {
    return __int_as_float(__builtin_amdgcn_update_dpp(
        0, __float_as_int(x), CTRL, 0xF, 0xF, true));   // bound_ctrl: 0-fill
}

__global__ __launch_bounds__(64)
void ctc_fwd(const int* __restrict__ y_true,
             const float* __restrict__ y_pred,
             float* __restrict__ out)
{
    const int b    = blockIdx.x;
    const int lane = threadIdx.x;   // 0..63

    const char* __restrict__ base =
        (const char*)(y_pred + (size_t)b * 512 * 128);

    const int   lab   = y_true[b * 64 + lane];     // label of state 2*lane+1
    const int   labp  = __shfl_up(lab, 1, 64);     // prologue-only DS
    const float skipf = (lane > 0 && lab != labp) ? 1.0f : 0.0f;
    const bool  l0    = (lane == 0);

    const int offL = lab * 4;      // byte offset of p[lab] within a row
    const int offB = 127 * 4;      // byte offset of p[blank]

    float pLab[32], pBlank[32];    // ring: slot r&31 holds row r

    // ---- prologue: rows 0..31 ----
    #pragma unroll
    for (int r = 0; r < 32; ++r) {
        pLab[r]   = *(const float*)(base + r * 512 + offL);
        pBlank[r] = *(const float*)(base + r * 512 + offB);
    }

    float aZ, aA, aB;              // alpha[0] (uniform), alpha[2i+1], alpha[2i+2]
    {
        float pb0 = pBlank[0] + EPSF;
        float pl0 = pLab[0]   + EPSF;
        aZ = pb0;                  // state 0
        aA = l0 ? pl0 : 0.0f;      // state 1 reachable only on lane 0
        aB = 0.0f;                 // states >= 2 unreachable at t=0
    }

    int   shift = 0;               // sum of applied log2 scale exponents
    float red   = 0.0f;            // staged wave-max (lane 63 authoritative)

    auto slot = [&](int t, int u, bool doLoad) {
        float pl = pLab[u]   + EPSF;
        float pb = pBlank[u] + EPSF;
        float upA = dpp_mov<0x138>(aA);    // alpha[2i-1]; lane0 -> 0 (correct)
        float upB = dpp_mov<0x138>(aB);    // alpha[2i]
        upB = l0 ? aZ : upB;               // lane0's s-1 is state 0
        float ts = aA + upB;
        ts = fmaf(skipf, upA, ts);         // + skip path
        float nA = pl * ts;
        float nB = pb * (aB + aA);
        aZ *= pb;
        aA = nA; aB = nB;

        if ((u & 7) == 3) {                // measure wave-max (applied at +4)
            float r = fmaxf(fmaxf(aA, aB), aZ);
            r = fmaxf(r, dpp_mov<0x111>(r));   // row_shr:1
            r = fmaxf(r, dpp_mov<0x112>(r));   // row_shr:2
            r = fmaxf(r, dpp_mov<0x114>(r));   // row_shr:4
            r = fmaxf(r, dpp_mov<0x118>(r));   // row_shr:8
            r = fmaxf(r, dpp_mov<0x142>(r));   // row_bcast:15
            r = fmaxf(r, dpp_mov<0x143>(r));   // row_bcast:31 -> lane63 = max
            red = r;
        }
        if ((u & 7) == 7) {                // apply uniform 2^k rescale
            int mb = __builtin_amdgcn_readlane(__float_as_int(red), 63);
            int e  = (mb >> 23) & 0xff;
            int f  = 314 - e;              // target: max -> ~2^60
            f = f < 1 ? 1 : (f > 254 ? 254 : f);
            float scale = __int_as_float(f << 23);
            shift += f - 127;
            aA *= scale; aB *= scale; aZ *= scale;
        }
        if (doLoad) {                      // row t+32 (consumed 32 slots later)
            int rn = t + 32; rn = rn > 511 ? 511 : rn;   // clamp dup, never consumed
            pLab[u]   = *(const float*)(base + rn * 512 + offL);
            pBlank[u] = *(const float*)(base + rn * 512 + offB);
        }
    };

    // ---- main: t = 1..480 (15 x 32 slots, with loads) ----
    for (int blk = 0; blk < 15; ++blk) {
        int t0 = 1 + blk * 32;
        #pragma unroll
        for (int i = 0; i < 32; ++i)
            slot(t0 + i, (1 + i) & 31, true);
    }
    // ---- epilogue: t = 481..511 (31 slots, no loads) ----
    #pragma unroll
    for (int i = 0; i < 31; ++i)
        slot(481 + i, (482 + i - 1) & 31, false);

    // ll = log(alpha[127] + alpha[128]) - shift*ln2; both on lane 63
    float s   = aA + aB;
    float ll2 = __builtin_amdgcn_logf(s);          // log2
    if (lane == 63) out[b] = ((float)shift - ll2) * LN2F;
}

extern "C" void kernel_launch(void* const* d_in, const int* in_sizes, int n_in,
                              void* d_out, int out_size, void* d_ws, size_t ws_size,
                              hipStream_t stream)
{
    const int*   y_true = (const int*)d_in[0];    // [B, L] int32
    const float* y_pred = (const float*)d_in[1];  // [B, T, C] float32
    float*       out    = (float*)d_out;          // [B, 1] float32

    const int B = out_size;   // 512
    ctc_fwd<<<dim3(B), dim3(64), 0, stream>>>(y_true, y_pred, out);
}